// Round 4
// baseline (107.236 us; speedup 1.0000x reference)
//
#include <hip/hip_runtime.h>
#include <hip/hip_fp16.h>

// MinEuclideanDistBlock: out[b,n] = min_w sum_c sqrt(max(||win||^2+||shp||^2-2*cross,0))
// B=64,C=3,L=2048,N=256,S=64,W=1985.
// R4: NO LDS staging in main kernel. Prep writes to d_ws: 2 parity-shifted bf16
// copies of x per (b,c) (so A-frag global loads are 4B-aligned dwordx4 from L1/L2),
// fp16 hw = -0.5*||win||^2 with hw = -65504 sentinel for w>=1985 (arithmetic masking,
// no per-iter cmp/cndmask), bf16 shapelets + hs = -0.5*||shp||^2; inits out to +inf.
// Main: grid 1024 = 64b x 8nt(32n) x 2wh(1024w); 4 waves; wave tile 32w x 32n; 8 iters.
// acc init = hw + hs so acc = -d2/2; d/sqrt2 = sqrt(max(-acc,0)); sqrt2 after min.

typedef float  v4f __attribute__((ext_vector_type(4)));
typedef unsigned int v4u __attribute__((ext_vector_type(4)));
typedef short  v8s __attribute__((ext_vector_type(8)));
typedef unsigned short u16;
typedef unsigned int   u32;
typedef unsigned long long u64;

#define N_ 256
#define C_ 3
#define L_ 2048
#define W_ 1985
#define XROW 2112          // elements per shifted copy (covers w<=2047 + k<=63)

// d_ws byte offsets
#define OFF_GX   0u               // [192][2][2112] u16 = 1,622,016 B
#define OFF_HW   1622016u         // [192][2048] half   =   786,432 B
#define OFF_SHP  2408448u         // [3][256][64] u16   =    98,304 B
#define OFF_HS   2506752u         // [768] f32          =     3,072 B

__device__ __forceinline__ u16 f2bf(float f) {
    u32 u = __builtin_bit_cast(u32, f);
    return (u16)((u + 0x7FFFu + ((u >> 16) & 1u)) >> 16);
}
__device__ __forceinline__ float bf2f(u16 b) {
    return __builtin_bit_cast(float, ((u32)b) << 16);
}
__device__ __forceinline__ u64 pack4(v4f v) {
    return (u64)f2bf(v[0]) | ((u64)f2bf(v[1]) << 16)
         | ((u64)f2bf(v[2]) << 32) | ((u64)f2bf(v[3]) << 48);
}

//============================ PREP ============================
// blocks 0..191: (b,c)=blk row task (+ out-init on blk<64); 192..194: shapelets.
__global__ __launch_bounds__(256)
void prep_kernel(const float* __restrict__ x, const float* __restrict__ shp,
                 u16* __restrict__ gx, u16* __restrict__ ghw,
                 u16* __restrict__ gshp, float* __restrict__ ghs,
                 u32* __restrict__ out_u)
{
    const int blk = blockIdx.x, tid = threadIdx.x;
    if (blk < 192) {
        __shared__ u16 xb[2176];                 // bf16 row + 128 zero pad
        const float* xr = x + (size_t)blk * L_;
        v4f a0 = *(const v4f*)(xr + tid * 8);
        v4f a1 = *(const v4f*)(xr + tid * 8 + 4);
        ((u64*)xb)[tid * 2]     = pack4(a0);
        ((u64*)xb)[tid * 2 + 1] = pack4(a1);
        if (tid < 32) ((u64*)xb)[512 + tid] = 0;
        if (blk < 64) out_u[blk * 256 + tid] = 0x7F800000u;   // +inf init
        __syncthreads();

        u16* g0 = gx + (size_t)blk * (2 * XROW);
        // copy0 (elems x[8u..8u+8)) and copy1 (elems x[8u+1..8u+9)), 264 16B-units each
        const u32* lw = (const u32*)xb;
        #pragma unroll 1
        for (int u = tid; u < 264; u += 256) {
            *(v4u*)(g0 + u * 8) = *(const v4u*)(xb + u * 8);
            u32 w0 = lw[4 * u], w1 = lw[4 * u + 1], w2 = lw[4 * u + 2],
                w3 = lw[4 * u + 3], w4 = lw[4 * u + 4];
            v4u o;
            o[0] = (w0 >> 16) | (w1 << 16);
            o[1] = (w1 >> 16) | (w2 << 16);
            o[2] = (w2 >> 16) | (w3 << 16);
            o[3] = (w3 >> 16) | (w4 << 16);
            *(v4u*)(g0 + XROW + u * 8) = o;
        }
        // hw = -0.5*||win||^2 (fp16), 8 windows/thread; sentinel -65504 for w>=1985
        {
            float e[72];
            #pragma unroll
            for (int j = 0; j < 18; ++j) {
                u64 ch = ((const u64*)xb)[tid * 2 + j];
                e[j * 4 + 0] = bf2f((u16)(ch));
                e[j * 4 + 1] = bf2f((u16)(ch >> 16));
                e[j * 4 + 2] = bf2f((u16)(ch >> 32));
                e[j * 4 + 3] = bf2f((u16)(ch >> 48));
            }
            float s = 0.f;
            #pragma unroll
            for (int i = 0; i < 64; ++i) s += e[i] * e[i];
            const int w0 = tid * 8;
            union { v4u v; __half h[8]; } hp;
            hp.h[0] = __float2half((w0 < W_) ? -0.5f * s : -65504.f);
            #pragma unroll
            for (int k = 1; k < 8; ++k) {
                s += e[63 + k] * e[63 + k] - e[k - 1] * e[k - 1];
                hp.h[k] = __float2half((w0 + k < W_) ? -0.5f * s : -65504.f);
            }
            *(v4u*)(ghw + (size_t)blk * L_ + w0) = hp.v;
        }
    } else if (blk < 195) {
        const int c = blk - 192;
        const int n = tid;
        const float* row = shp + ((size_t)c * N_ + n) * 64;
        float sacc = 0.f;
        #pragma unroll
        for (int k = 0; k < 8; ++k) {
            v4f a0 = *(const v4f*)(row + k * 8);
            v4f a1 = *(const v4f*)(row + k * 8 + 4);
            u64 p0 = pack4(a0), p1 = pack4(a1);
            union { u64 u[2]; v4u v; } st; st.u[0] = p0; st.u[1] = p1;
            *(v4u*)(gshp + ((size_t)c * N_ + n) * 64 + k * 8) = st.v;
            #pragma unroll
            for (int j = 0; j < 4; ++j) {
                float e0 = bf2f((u16)(p0 >> (16 * j)));
                float e1 = bf2f((u16)(p1 >> (16 * j)));
                sacc += e0 * e0 + e1 * e1;
            }
        }
        ghs[c * N_ + n] = -0.5f * sacc;
    }
}

//============================ MAIN ============================
__global__ __launch_bounds__(256, 4)
void shapelet_min_kernel(const u16* __restrict__ gx, const u16* __restrict__ ghw,
                         const u16* __restrict__ gshp, const float* __restrict__ ghs,
                         u32* __restrict__ out_u)
{
    __shared__ float red[4][32];

    const int tid  = threadIdx.x;
    const int wave = tid >> 6;
    const int lane = tid & 63;
    const int m    = lane & 15;
    const int q    = lane >> 4;
    const int p    = m & 1;          // which parity copy
    const int wh   = blockIdx.x & 1;
    const int nb   = (blockIdx.x >> 1) & 7;
    const int b    = blockIdx.x >> 4;
    const int n0   = nb << 5;
    const int wstart = wh << 10;

    // B fragments + hs straight from global (L2-resident, loop-invariant)
    v8s   bfr[C_][2][2];
    float hs[C_][2];
    #pragma unroll
    for (int c = 0; c < C_; ++c)
        #pragma unroll
        for (int nt = 0; nt < 2; ++nt) {
            int n = n0 + nt * 16 + m;
            hs[c][nt] = ghs[c * N_ + n];
            #pragma unroll
            for (int h = 0; h < 2; ++h)
                bfr[c][nt][h] = *(const v8s*)(gshp + ((size_t)(c * N_ + n) * 64 + h * 32 + q * 8));
        }

    // per-c base pointers; all per-iter deltas fit in 13-bit immediate offsets
    const u16* pa[C_];
    const u16* pw[C_];
    #pragma unroll
    for (int c = 0; c < C_; ++c) {
        pa[c] = gx  + ((size_t)(b * 3 + c) * 2 + p) * XROW + (wstart + wave * 32 + m - p + q * 8);
        pw[c] = ghw + (size_t)(b * 3 + c) * L_ + (wstart + wave * 32 + q * 4);
    }

    float mins[2] = {1e30f, 1e30f};

    #pragma unroll 1
    for (int it = 0; it < 8; ++it) {
        const int iof = it * 128;
        float sums[2][2][4];
        #pragma unroll
        for (int mt = 0; mt < 2; ++mt)
            #pragma unroll
            for (int nt = 0; nt < 2; ++nt)
                #pragma unroll
                for (int g = 0; g < 4; ++g) sums[mt][nt][g] = 0.f;

        #pragma unroll
        for (int c = 0; c < C_; ++c) {
            // acc init = hw + hs (both pre-scaled by -0.5); sentinel hw kills padded w
            v4f acc[2][2];
            #pragma unroll
            for (int mt = 0; mt < 2; ++mt) {
                union { u64 u; __half h4[4]; } wq;
                __builtin_memcpy(&wq.u, pw[c] + iof + mt * 16, 8);
                #pragma unroll
                for (int g = 0; g < 4; ++g) {
                    float hv = __half2float(wq.h4[g]);
                    acc[mt][0][g] = hv + hs[c][0];
                    acc[mt][1][g] = hv + hs[c][1];
                }
            }
            #pragma unroll
            for (int h = 0; h < 2; ++h) {
                v8s afr[2];
                #pragma unroll
                for (int mt = 0; mt < 2; ++mt)
                    __builtin_memcpy(&afr[mt], pa[c] + iof + mt * 16 + h * 32, 16);
                #pragma unroll
                for (int mt = 0; mt < 2; ++mt)
                    #pragma unroll
                    for (int nt = 0; nt < 2; ++nt)
                        acc[mt][nt] = __builtin_amdgcn_mfma_f32_16x16x32_bf16(
                            afr[mt], bfr[c][nt][h], acc[mt][nt], 0, 0, 0);
            }
            #pragma unroll
            for (int mt = 0; mt < 2; ++mt)
                #pragma unroll
                for (int nt = 0; nt < 2; ++nt)
                    #pragma unroll
                    for (int g = 0; g < 4; ++g)
                        sums[mt][nt][g] += __builtin_amdgcn_sqrtf(fmaxf(-acc[mt][nt][g], 0.f));
        }
        #pragma unroll
        for (int mt = 0; mt < 2; ++mt)
            #pragma unroll
            for (int nt = 0; nt < 2; ++nt)
                #pragma unroll
                for (int g = 0; g < 4; ++g)
                    mins[nt] = fminf(mins[nt], sums[mt][nt][g]);
    }

    //=== Reduce across quads (same n, different w-rows), waves, then atomicMin ===
    #pragma unroll
    for (int nt = 0; nt < 2; ++nt) {
        mins[nt] = fminf(mins[nt], __shfl_xor(mins[nt], 16));
        mins[nt] = fminf(mins[nt], __shfl_xor(mins[nt], 32));
    }
    if (lane < 16) { red[wave][m] = mins[0]; red[wave][16 + m] = mins[1]; }
    __syncthreads();
    if (tid < 32) {
        float v = fminf(fminf(red[0][tid], red[1][tid]),
                        fminf(red[2][tid], red[3][tid]));
        atomicMin(out_u + (size_t)b * N_ + n0 + tid,
                  __float_as_uint(v * 1.41421356237f));
    }
}

extern "C" void kernel_launch(void* const* d_in, const int* in_sizes, int n_in,
                              void* d_out, int out_size, void* d_ws, size_t ws_size,
                              hipStream_t stream) {
    const float* x   = (const float*)d_in[0];   // (64, 3, 2048) fp32
    const float* shp = (const float*)d_in[1];   // (3, 256, 64) fp32
    u32* out_u       = (u32*)d_out;             // (64, 1, 256) fp32 via u32 atomicMin

    char* ws = (char*)d_ws;
    u16*   gx   = (u16*)(ws + OFF_GX);
    u16*   ghw  = (u16*)(ws + OFF_HW);
    u16*   gshp = (u16*)(ws + OFF_SHP);
    float* ghs  = (float*)(ws + OFF_HS);

    hipLaunchKernelGGL(prep_kernel, dim3(195), dim3(256), 0, stream,
                       x, shp, gx, ghw, gshp, ghs, out_u);
    hipLaunchKernelGGL(shapelet_min_kernel, dim3(1024), dim3(256), 0, stream,
                       gx, ghw, gshp, ghs, out_u);
}